// Round 1
// baseline (757.265 us; speedup 1.0000x reference)
//
#include <hip/hip_runtime.h>
#include <stdint.h>

#define B_ 8
#define C_ 256
#define D_ 128
#define N_ 4096

typedef __bf16 bf16x8 __attribute__((ext_vector_type(8)));
typedef uint16_t u16x8 __attribute__((ext_vector_type(8)));
typedef uint16_t u16x4 __attribute__((ext_vector_type(4)));
typedef float f32x4 __attribute__((ext_vector_type(4)));

__device__ inline uint16_t f2bf(float x) {
    union { float f; uint32_t u; } v; v.f = x;
    uint32_t u = v.u;
    return (uint16_t)((u + 0x7FFFu + ((u >> 16) & 1u)) >> 16);
}

// ---------------- prep: fp32 weights -> bf16 (scale 1/sqrt(D) folded into W_theta)
__global__ __launch_bounds__(256) void prep_weights(
    const float* __restrict__ wt, const float* __restrict__ wp,
    const float* __restrict__ wg, const float* __restrict__ wo,
    uint16_t* __restrict__ bwt, uint16_t* __restrict__ bwp,
    uint16_t* __restrict__ bwg, uint16_t* __restrict__ bwo)
{
    int i = blockIdx.x * 256 + threadIdx.x;   // 0..32767
    const float scale = 0.08838834764831845f; // 1/sqrt(128)
    bwt[i] = f2bf(wt[i] * scale);
    bwp[i] = f2bf(wp[i]);
    bwg[i] = f2bf(wg[i]);
    bwo[i] = f2bf(wo[i]);
}

// ---------------- projections: z=0 qp[B][N][D], z=1 kp[B][N][D], z=2 vpT[B][D][N]
// GEMM orientation: A = W[d][c] (M=d), B = src[c][n] (N-side = n), K = C.
__global__ __launch_bounds__(256) void proj_kernel(
    const float* __restrict__ q, const float* __restrict__ k, const float* __restrict__ v,
    const uint16_t* __restrict__ bwt, const uint16_t* __restrict__ bwp, const uint16_t* __restrict__ bwg,
    uint16_t* __restrict__ qp, uint16_t* __restrict__ kp, uint16_t* __restrict__ vpT)
{
    const int which = blockIdx.z;
    const float* src = (which == 0) ? q : ((which == 1) ? k : v);
    const uint16_t* w = (which == 0) ? bwt : ((which == 1) ? bwp : bwg);
    const int b   = blockIdx.y;
    const int n0  = blockIdx.x * 64;
    const int wav = threadIdx.x >> 6;
    const int lane = threadIdx.x & 63;
    const int col = lane & 15;
    const int quad = lane >> 4;
    const int n = n0 + wav * 16 + col;

    const float* srcb = src + (size_t)b * C_ * N_;

    f32x4 acc[8];
#pragma unroll
    for (int mf = 0; mf < 8; ++mf) acc[mf] = (f32x4){0.f, 0.f, 0.f, 0.f};

    for (int kc = 0; kc < 8; ++kc) {
        const int cbase = kc * 32 + quad * 8;
        // B-frag: src[c][n], lane holds k = cbase..cbase+7 at its n (strided fp32 loads)
        u16x8 bb;
#pragma unroll
        for (int j = 0; j < 8; ++j)
            bb[j] = f2bf(srcb[(size_t)(cbase + j) * N_ + n]);
        bf16x8 bfrag = __builtin_bit_cast(bf16x8, bb);
#pragma unroll
        for (int mf = 0; mf < 8; ++mf) {
            // A-frag: w[d = mf*16+col][cbase .. cbase+7], contiguous 16B
            bf16x8 afrag = *(const bf16x8*)(w + (size_t)(mf * 16 + col) * C_ + cbase);
            acc[mf] = __builtin_amdgcn_mfma_f32_16x16x32_bf16(afrag, bfrag, acc[mf], 0, 0, 0);
        }
    }

    if (which < 2) {
        uint16_t* dst = (which == 0) ? qp : kp;          // [B][N][D], d contiguous
        uint16_t* base = dst + ((size_t)b * N_ + n) * D_;
#pragma unroll
        for (int mf = 0; mf < 8; ++mf) {
            u16x4 pk;
#pragma unroll
            for (int r = 0; r < 4; ++r) pk[r] = f2bf(acc[mf][r]);
            *(u16x4*)(base + mf * 16 + quad * 4) = pk;   // 4 consecutive d, 8B store
        }
    } else {
        uint16_t* base = vpT + (size_t)b * D_ * N_;       // [B][D][N], n contiguous
#pragma unroll
        for (int mf = 0; mf < 8; ++mf)
#pragma unroll
            for (int r = 0; r < 4; ++r) {
                int d = mf * 16 + quad * 4 + r;
                base[(size_t)d * N_ + n] = f2bf(acc[mf][r]);
            }
    }
}

// ---------------- pass 1: inv_denom[b][m] = 1 / sum_n exp(S[n][m])
// one block owns m-stripe of 64 (4 m-frags), KP frags hoisted to registers; waves split n.
__global__ __launch_bounds__(256) void pass1_denom(
    const uint16_t* __restrict__ qp, const uint16_t* __restrict__ kp,
    float* __restrict__ inv_denom)
{
    const int b  = blockIdx.y;
    const int m0 = blockIdx.x * 64;
    const int wav = threadIdx.x >> 6;
    const int lane = threadIdx.x & 63;
    const int col = lane & 15;
    const int quad = lane >> 4;

    const uint16_t* qpb = qp + (size_t)b * N_ * D_;
    const uint16_t* kpb = kp + (size_t)b * N_ * D_;

    bf16x8 bfr[4][4];
#pragma unroll
    for (int mf = 0; mf < 4; ++mf)
#pragma unroll
        for (int kc = 0; kc < 4; ++kc)
            bfr[mf][kc] = *(const bf16x8*)(kpb + (size_t)(m0 + mf * 16 + col) * D_ + kc * 32 + quad * 8);

    float colsum[4] = {0.f, 0.f, 0.f, 0.f};

    for (int it = 0; it < 64; ++it) {
        const int nbase = it * 64 + wav * 16;
        bf16x8 afr[4];
#pragma unroll
        for (int kc = 0; kc < 4; ++kc)
            afr[kc] = *(const bf16x8*)(qpb + (size_t)(nbase + col) * D_ + kc * 32 + quad * 8);
#pragma unroll
        for (int mf = 0; mf < 4; ++mf) {
            f32x4 acc = (f32x4){0.f, 0.f, 0.f, 0.f};
#pragma unroll
            for (int kc = 0; kc < 4; ++kc)
                acc = __builtin_amdgcn_mfma_f32_16x16x32_bf16(afr[kc], bfr[mf][kc], acc, 0, 0, 0);
#pragma unroll
            for (int r = 0; r < 4; ++r)
                colsum[mf] += __expf(acc[r]);
        }
    }

    __shared__ float cs[4][64];
#pragma unroll
    for (int mf = 0; mf < 4; ++mf) {
        float s = colsum[mf];
        s += __shfl_down(s, 16, 64);
        s += __shfl_down(s, 32, 64);
        if (quad == 0) cs[wav][mf * 16 + col] = s;
    }
    __syncthreads();
    if (threadIdx.x < 64) {
        float s = cs[0][threadIdx.x] + cs[1][threadIdx.x] + cs[2][threadIdx.x] + cs[3][threadIdx.x];
        inv_denom[(size_t)b * N_ + m0 + threadIdx.x] = 1.0f / s;
    }
}

// ---------------- pass 2: O[n][d] = sum_m exp(S[n][m]) * inv_denom[m] * vp[m][d]
// block = 64 n-rows (wave owns 16), loop m in chunks of 32; P goes C-layout -> LDS -> A-layout.
__global__ __launch_bounds__(256) void pass2_attn(
    const uint16_t* __restrict__ qp, const uint16_t* __restrict__ kp,
    const uint16_t* __restrict__ vpT, const float* __restrict__ inv_denom,
    uint16_t* __restrict__ obuf)
{
    const int b  = blockIdx.y;
    const int n0 = blockIdx.x * 64;
    const int wav = threadIdx.x >> 6;
    const int lane = threadIdx.x & 63;
    const int col = lane & 15;
    const int quad = lane >> 4;

    const uint16_t* qpb = qp + (size_t)b * N_ * D_;
    const uint16_t* kpb = kp + (size_t)b * N_ * D_;
    const uint16_t* vtb = vpT + (size_t)b * D_ * N_;
    const float* invd = inv_denom + (size_t)b * N_;

    __shared__ __align__(16) uint16_t plds_all[4][16][40];  // +8 pad breaks b128 read conflicts
    uint16_t (*plds)[40] = plds_all[wav];

    const int nrow = n0 + wav * 16 + col;
    bf16x8 qfr[4];
#pragma unroll
    for (int kc = 0; kc < 4; ++kc)
        qfr[kc] = *(const bf16x8*)(qpb + (size_t)nrow * D_ + kc * 32 + quad * 8);

    f32x4 oacc[8];
#pragma unroll
    for (int df = 0; df < 8; ++df) oacc[df] = (f32x4){0.f, 0.f, 0.f, 0.f};

    for (int m0 = 0; m0 < N_; m0 += 32) {
#pragma unroll
        for (int f = 0; f < 2; ++f) {
            f32x4 sacc = (f32x4){0.f, 0.f, 0.f, 0.f};
#pragma unroll
            for (int kc = 0; kc < 4; ++kc) {
                bf16x8 bfr = *(const bf16x8*)(kpb + (size_t)(m0 + f * 16 + col) * D_ + kc * 32 + quad * 8);
                sacc = __builtin_amdgcn_mfma_f32_16x16x32_bf16(qfr[kc], bfr, sacc, 0, 0, 0);
            }
            const float inv = invd[m0 + f * 16 + col];   // lane's m column
#pragma unroll
            for (int r = 0; r < 4; ++r)
                plds[quad * 4 + r][f * 16 + col] = f2bf(__expf(sacc[r]) * inv);
        }
        __syncthreads();   // orders LDS write -> read (per-wave region; barrier is uniform)
        bf16x8 pfrag = *(const bf16x8*)&plds[col][quad * 8];   // A-layout: n=col, k=m chunk
#pragma unroll
        for (int df = 0; df < 8; ++df) {
            bf16x8 vfr = *(const bf16x8*)(vtb + (size_t)(df * 16 + col) * N_ + m0 + quad * 8);
            oacc[df] = __builtin_amdgcn_mfma_f32_16x16x32_bf16(pfrag, vfr, oacc[df], 0, 0, 0);
        }
        __syncthreads();   // protect plds against next-iter overwrite
    }

    uint16_t* ob = obuf + ((size_t)b * N_ + n0 + wav * 16) * D_;   // [B][N][D]
#pragma unroll
    for (int df = 0; df < 8; ++df)
#pragma unroll
        for (int r = 0; r < 4; ++r)
            ob[(size_t)(quad * 4 + r) * D_ + df * 16 + col] = f2bf(oacc[df][r]);
}

// ---------------- pass 3: out[b][c][n] = v[b][c][n] + sum_d W_out[c][d] * O[n][d]
__global__ __launch_bounds__(256) void pass3_out(
    const uint16_t* __restrict__ obuf, const uint16_t* __restrict__ bwo,
    const float* __restrict__ v, float* __restrict__ out)
{
    const int b  = blockIdx.y;
    const int n0 = blockIdx.x * 64;
    const int wav = threadIdx.x >> 6;
    const int lane = threadIdx.x & 63;
    const int col = lane & 15;
    const int quad = lane >> 4;
    const int n = n0 + wav * 16 + col;

    const uint16_t* ob = obuf + (size_t)b * N_ * D_;
    const float* vb = v + (size_t)b * C_ * N_;
    float* outb = out + (size_t)b * C_ * N_;

    bf16x8 bfr[4];
#pragma unroll
    for (int kc = 0; kc < 4; ++kc)
        bfr[kc] = *(const bf16x8*)(ob + (size_t)n * D_ + kc * 32 + quad * 8);

#pragma unroll
    for (int cf = 0; cf < 16; ++cf) {
        f32x4 acc = (f32x4){0.f, 0.f, 0.f, 0.f};
#pragma unroll
        for (int kc = 0; kc < 4; ++kc) {
            bf16x8 afr = *(const bf16x8*)(bwo + (size_t)(cf * 16 + col) * D_ + kc * 32 + quad * 8);
            acc = __builtin_amdgcn_mfma_f32_16x16x32_bf16(afr, bfr[kc], acc, 0, 0, 0);
        }
#pragma unroll
        for (int r = 0; r < 4; ++r) {
            const int c = cf * 16 + quad * 4 + r;
            const size_t idx = (size_t)c * N_ + n;
            outb[idx] = vb[idx] + acc[r];
        }
    }
}

extern "C" void kernel_launch(void* const* d_in, const int* in_sizes, int n_in,
                              void* d_out, int out_size, void* d_ws, size_t ws_size,
                              hipStream_t stream) {
    const float* q  = (const float*)d_in[0];
    const float* k  = (const float*)d_in[1];
    const float* v  = (const float*)d_in[2];
    const float* wt = (const float*)d_in[3];
    const float* wp = (const float*)d_in[4];
    const float* wg = (const float*)d_in[5];
    const float* wo = (const float*)d_in[6];
    float* out = (float*)d_out;

    const size_t PROJ = (size_t)B_ * N_ * D_;   // 4,194,304 elems
    uint16_t* qp   = (uint16_t*)d_ws;
    uint16_t* kp   = qp + PROJ;
    uint16_t* vpT  = kp + PROJ;
    uint16_t* obuf = vpT + PROJ;
    uint16_t* bwt  = obuf + PROJ;
    uint16_t* bwp  = bwt + (size_t)D_ * C_;
    uint16_t* bwg  = bwp + (size_t)D_ * C_;
    uint16_t* bwo  = bwg + (size_t)D_ * C_;
    float* invd    = (float*)(bwo + (size_t)D_ * C_);
    // total ws use: 4*8MB + 4*64KB + 128KB ≈ 34 MB

    prep_weights<<<dim3(128), 256, 0, stream>>>(wt, wp, wg, wo, bwt, bwp, bwg, bwo);
    proj_kernel<<<dim3(N_ / 64, B_, 3), 256, 0, stream>>>(q, k, v, bwt, bwp, bwg, qp, kp, vpT);
    pass1_denom<<<dim3(N_ / 64, B_), 256, 0, stream>>>(qp, kp, invd);
    pass2_attn<<<dim3(N_ / 64, B_), 256, 0, stream>>>(qp, kp, vpT, invd, obuf);
    pass3_out<<<dim3(N_ / 64, B_), 256, 0, stream>>>(obuf, bwo, v, out);
}

// Round 2
// 729.353 us; speedup vs baseline: 1.0383x; 1.0383x over previous
//
#include <hip/hip_runtime.h>
#include <stdint.h>

#define B_ 8
#define C_ 256
#define D_ 128
#define N_ 4096

typedef __bf16 bf16x8 __attribute__((ext_vector_type(8)));
typedef uint16_t u16x8 __attribute__((ext_vector_type(8)));
typedef uint16_t u16x4 __attribute__((ext_vector_type(4)));
typedef float f32x4 __attribute__((ext_vector_type(4)));

__device__ inline uint16_t f2bf(float x) {
    union { float f; uint32_t u; } v; v.f = x;
    uint32_t u = v.u;
    return (uint16_t)((u + 0x7FFFu + ((u >> 16) & 1u)) >> 16);
}

// ---------------- prep: fp32 weights -> bf16 (scale 1/sqrt(D) folded into W_theta)
__global__ __launch_bounds__(256) void prep_weights(
    const float* __restrict__ wt, const float* __restrict__ wp,
    const float* __restrict__ wg, const float* __restrict__ wo,
    uint16_t* __restrict__ bwt, uint16_t* __restrict__ bwp,
    uint16_t* __restrict__ bwg, uint16_t* __restrict__ bwo)
{
    int i = blockIdx.x * 256 + threadIdx.x;   // 0..32767
    const float scale = 0.08838834764831845f; // 1/sqrt(128)
    bwt[i] = f2bf(wt[i] * scale);
    bwp[i] = f2bf(wp[i]);
    bwg[i] = f2bf(wg[i]);
    bwo[i] = f2bf(wo[i]);
}

// ---------------- projections: z=0 qp[B][N][D], z=1 kp[B][N][D], z=2 vpT[B][D][N]
// GEMM orientation: A = W[d][c] (M=d), B = src[c][n] (N-side = n), K = C.
__global__ __launch_bounds__(256) void proj_kernel(
    const float* __restrict__ q, const float* __restrict__ k, const float* __restrict__ v,
    const uint16_t* __restrict__ bwt, const uint16_t* __restrict__ bwp, const uint16_t* __restrict__ bwg,
    uint16_t* __restrict__ qp, uint16_t* __restrict__ kp, uint16_t* __restrict__ vpT)
{
    const int which = blockIdx.z;
    const float* src = (which == 0) ? q : ((which == 1) ? k : v);
    const uint16_t* w = (which == 0) ? bwt : ((which == 1) ? bwp : bwg);
    const int b   = blockIdx.y;
    const int n0  = blockIdx.x * 64;
    const int wav = threadIdx.x >> 6;
    const int lane = threadIdx.x & 63;
    const int col = lane & 15;
    const int quad = lane >> 4;
    const int n = n0 + wav * 16 + col;

    const float* srcb = src + (size_t)b * C_ * N_;

    f32x4 acc[8];
#pragma unroll
    for (int mf = 0; mf < 8; ++mf) acc[mf] = (f32x4){0.f, 0.f, 0.f, 0.f};

    for (int kc = 0; kc < 8; ++kc) {
        const int cbase = kc * 32 + quad * 8;
        // B-frag: src[c][n], lane holds k = cbase..cbase+7 at its n (strided fp32 loads)
        u16x8 bb;
#pragma unroll
        for (int j = 0; j < 8; ++j)
            bb[j] = f2bf(srcb[(size_t)(cbase + j) * N_ + n]);
        bf16x8 bfrag = __builtin_bit_cast(bf16x8, bb);
#pragma unroll
        for (int mf = 0; mf < 8; ++mf) {
            // A-frag: w[d = mf*16+col][cbase .. cbase+7], contiguous 16B
            bf16x8 afrag = *(const bf16x8*)(w + (size_t)(mf * 16 + col) * C_ + cbase);
            acc[mf] = __builtin_amdgcn_mfma_f32_16x16x32_bf16(afrag, bfrag, acc[mf], 0, 0, 0);
        }
    }

    if (which < 2) {
        uint16_t* dst = (which == 0) ? qp : kp;          // [B][N][D], d contiguous
        uint16_t* base = dst + ((size_t)b * N_ + n) * D_;
#pragma unroll
        for (int mf = 0; mf < 8; ++mf) {
            u16x4 pk;
#pragma unroll
            for (int r = 0; r < 4; ++r) pk[r] = f2bf(acc[mf][r]);
            *(u16x4*)(base + mf * 16 + quad * 4) = pk;   // 4 consecutive d, 8B store
        }
    } else {
        uint16_t* base = vpT + (size_t)b * D_ * N_;       // [B][D][N], n contiguous
#pragma unroll
        for (int mf = 0; mf < 8; ++mf)
#pragma unroll
            for (int r = 0; r < 4; ++r) {
                int d = mf * 16 + quad * 4 + r;
                base[(size_t)d * N_ + n] = f2bf(acc[mf][r]);
            }
    }
}

// ---------------- pass 1: inv_denom[b][m] = 1 / sum_n exp(S[n][m])
// one block owns m-stripe of 64 (4 m-frags), KP frags hoisted to registers; waves split n.
__global__ __launch_bounds__(256) void pass1_denom(
    const uint16_t* __restrict__ qp, const uint16_t* __restrict__ kp,
    float* __restrict__ inv_denom)
{
    const int b  = blockIdx.y;
    const int m0 = blockIdx.x * 64;
    const int wav = threadIdx.x >> 6;
    const int lane = threadIdx.x & 63;
    const int col = lane & 15;
    const int quad = lane >> 4;

    const uint16_t* qpb = qp + (size_t)b * N_ * D_;
    const uint16_t* kpb = kp + (size_t)b * N_ * D_;

    bf16x8 bfr[4][4];
#pragma unroll
    for (int mf = 0; mf < 4; ++mf)
#pragma unroll
        for (int kc = 0; kc < 4; ++kc)
            bfr[mf][kc] = *(const bf16x8*)(kpb + (size_t)(m0 + mf * 16 + col) * D_ + kc * 32 + quad * 8);

    float colsum[4] = {0.f, 0.f, 0.f, 0.f};

    for (int it = 0; it < 64; ++it) {
        const int nbase = it * 64 + wav * 16;
        bf16x8 afr[4];
#pragma unroll
        for (int kc = 0; kc < 4; ++kc)
            afr[kc] = *(const bf16x8*)(qpb + (size_t)(nbase + col) * D_ + kc * 32 + quad * 8);
#pragma unroll
        for (int mf = 0; mf < 4; ++mf) {
            f32x4 acc = (f32x4){0.f, 0.f, 0.f, 0.f};
#pragma unroll
            for (int kc = 0; kc < 4; ++kc)
                acc = __builtin_amdgcn_mfma_f32_16x16x32_bf16(afr[kc], bfr[mf][kc], acc, 0, 0, 0);
#pragma unroll
            for (int r = 0; r < 4; ++r)
                colsum[mf] += __expf(acc[r]);
        }
    }

    __shared__ float cs[4][64];
#pragma unroll
    for (int mf = 0; mf < 4; ++mf) {
        float s = colsum[mf];
        s += __shfl_down(s, 16, 64);
        s += __shfl_down(s, 32, 64);
        if (quad == 0) cs[wav][mf * 16 + col] = s;
    }
    __syncthreads();
    if (threadIdx.x < 64) {
        float s = cs[0][threadIdx.x] + cs[1][threadIdx.x] + cs[2][threadIdx.x] + cs[3][threadIdx.x];
        inv_denom[(size_t)b * N_ + m0 + threadIdx.x] = 1.0f / s;
    }
}

// ---------------- pass 2: O[n][d] = sum_m exp(S[n][m]) * inv_denom[m] * vp[m][d]
// block = 64 n-rows (wave owns 16), loop m in chunks of 32; P goes C-layout -> LDS -> A-layout.
// NOTE: plds region is strictly per-wave -> NO __syncthreads in the m-loop.
// Same-wave ds_write -> ds_read ordering is guaranteed by in-order DS execution
// + compiler-inserted lgkmcnt waits (it cannot disprove aliasing within plds_all).
__global__ __launch_bounds__(256) void pass2_attn(
    const uint16_t* __restrict__ qp, const uint16_t* __restrict__ kp,
    const uint16_t* __restrict__ vpT, const float* __restrict__ inv_denom,
    uint16_t* __restrict__ obuf)
{
    const int b  = blockIdx.y;
    const int n0 = blockIdx.x * 64;
    const int wav = threadIdx.x >> 6;
    const int lane = threadIdx.x & 63;
    const int col = lane & 15;
    const int quad = lane >> 4;

    const uint16_t* qpb = qp + (size_t)b * N_ * D_;
    const uint16_t* kpb = kp + (size_t)b * N_ * D_;
    const uint16_t* vtb = vpT + (size_t)b * D_ * N_;
    const float* invd = inv_denom + (size_t)b * N_;

    __shared__ __align__(16) uint16_t plds_all[4][16][40];  // +8 pad breaks b128 read conflicts
    uint16_t (*plds)[40] = plds_all[wav];

    const int nrow = n0 + wav * 16 + col;
    bf16x8 qfr[4];
#pragma unroll
    for (int kc = 0; kc < 4; ++kc)
        qfr[kc] = *(const bf16x8*)(qpb + (size_t)nrow * D_ + kc * 32 + quad * 8);

    f32x4 oacc[8];
#pragma unroll
    for (int df = 0; df < 8; ++df) oacc[df] = (f32x4){0.f, 0.f, 0.f, 0.f};

    for (int m0 = 0; m0 < N_; m0 += 32) {
#pragma unroll
        for (int f = 0; f < 2; ++f) {
            f32x4 sacc = (f32x4){0.f, 0.f, 0.f, 0.f};
#pragma unroll
            for (int kc = 0; kc < 4; ++kc) {
                bf16x8 bfr = *(const bf16x8*)(kpb + (size_t)(m0 + f * 16 + col) * D_ + kc * 32 + quad * 8);
                sacc = __builtin_amdgcn_mfma_f32_16x16x32_bf16(qfr[kc], bfr, sacc, 0, 0, 0);
            }
            const float inv = invd[m0 + f * 16 + col];   // lane's m column
#pragma unroll
            for (int r = 0; r < 4; ++r)
                plds[quad * 4 + r][f * 16 + col] = f2bf(__expf(sacc[r]) * inv);
        }
        // no barrier: per-wave LDS region, in-order DS + lgkmcnt ordering suffices
        bf16x8 pfrag = *(const bf16x8*)&plds[col][quad * 8];   // A-layout: n=col, k=m chunk
#pragma unroll
        for (int df = 0; df < 8; ++df) {
            bf16x8 vfr = *(const bf16x8*)(vtb + (size_t)(df * 16 + col) * N_ + m0 + quad * 8);
            oacc[df] = __builtin_amdgcn_mfma_f32_16x16x32_bf16(pfrag, vfr, oacc[df], 0, 0, 0);
        }
        // no barrier: next-iter ds_writes stay ordered behind this iter's ds_read
    }

    uint16_t* ob = obuf + ((size_t)b * N_ + n0 + wav * 16) * D_;   // [B][N][D]
#pragma unroll
    for (int df = 0; df < 8; ++df)
#pragma unroll
        for (int r = 0; r < 4; ++r)
            ob[(size_t)(quad * 4 + r) * D_ + df * 16 + col] = f2bf(oacc[df][r]);
}

// ---------------- pass 3: out[b][c][n] = v[b][c][n] + sum_d W_out[c][d] * O[n][d]
__global__ __launch_bounds__(256) void pass3_out(
    const uint16_t* __restrict__ obuf, const uint16_t* __restrict__ bwo,
    const float* __restrict__ v, float* __restrict__ out)
{
    const int b  = blockIdx.y;
    const int n0 = blockIdx.x * 64;
    const int wav = threadIdx.x >> 6;
    const int lane = threadIdx.x & 63;
    const int col = lane & 15;
    const int quad = lane >> 4;
    const int n = n0 + wav * 16 + col;

    const uint16_t* ob = obuf + (size_t)b * N_ * D_;
    const float* vb = v + (size_t)b * C_ * N_;
    float* outb = out + (size_t)b * C_ * N_;

    bf16x8 bfr[4];
#pragma unroll
    for (int kc = 0; kc < 4; ++kc)
        bfr[kc] = *(const bf16x8*)(ob + (size_t)n * D_ + kc * 32 + quad * 8);

#pragma unroll
    for (int cf = 0; cf < 16; ++cf) {
        f32x4 acc = (f32x4){0.f, 0.f, 0.f, 0.f};
#pragma unroll
        for (int kc = 0; kc < 4; ++kc) {
            bf16x8 afr = *(const bf16x8*)(bwo + (size_t)(cf * 16 + col) * D_ + kc * 32 + quad * 8);
            acc = __builtin_amdgcn_mfma_f32_16x16x32_bf16(afr, bfr[kc], acc, 0, 0, 0);
        }
#pragma unroll
        for (int r = 0; r < 4; ++r) {
            const int c = cf * 16 + quad * 4 + r;
            const size_t idx = (size_t)c * N_ + n;
            outb[idx] = vb[idx] + acc[r];
        }
    }
}

extern "C" void kernel_launch(void* const* d_in, const int* in_sizes, int n_in,
                              void* d_out, int out_size, void* d_ws, size_t ws_size,
                              hipStream_t stream) {
    const float* q  = (const float*)d_in[0];
    const float* k  = (const float*)d_in[1];
    const float* v  = (const float*)d_in[2];
    const float* wt = (const float*)d_in[3];
    const float* wp = (const float*)d_in[4];
    const float* wg = (const float*)d_in[5];
    const float* wo = (const float*)d_in[6];
    float* out = (float*)d_out;

    const size_t PROJ = (size_t)B_ * N_ * D_;   // 4,194,304 elems
    uint16_t* qp   = (uint16_t*)d_ws;
    uint16_t* kp   = qp + PROJ;
    uint16_t* vpT  = kp + PROJ;
    uint16_t* obuf = vpT + PROJ;
    uint16_t* bwt  = obuf + PROJ;
    uint16_t* bwp  = bwt + (size_t)D_ * C_;
    uint16_t* bwg  = bwp + (size_t)D_ * C_;
    uint16_t* bwo  = bwg + (size_t)D_ * C_;
    float* invd    = (float*)(bwo + (size_t)D_ * C_);
    // total ws use: 4*8MB + 4*64KB + 128KB ≈ 34 MB

    prep_weights<<<dim3(128), 256, 0, stream>>>(wt, wp, wg, wo, bwt, bwp, bwg, bwo);
    proj_kernel<<<dim3(N_ / 64, B_, 3), 256, 0, stream>>>(q, k, v, bwt, bwp, bwg, qp, kp, vpT);
    pass1_denom<<<dim3(N_ / 64, B_), 256, 0, stream>>>(qp, kp, invd);
    pass2_attn<<<dim3(N_ / 64, B_), 256, 0, stream>>>(qp, kp, vpT, invd, obuf);
    pass3_out<<<dim3(N_ / 64, B_), 256, 0, stream>>>(obuf, bwo, v, out);
}

// Round 3
// 728.480 us; speedup vs baseline: 1.0395x; 1.0012x over previous
//
#include <hip/hip_runtime.h>
#include <stdint.h>

#define B_ 8
#define C_ 256
#define D_ 128
#define N_ 4096

typedef __bf16 bf16x8 __attribute__((ext_vector_type(8)));
typedef uint16_t u16x8 __attribute__((ext_vector_type(8)));
typedef uint16_t u16x4 __attribute__((ext_vector_type(4)));
typedef float f32x4 __attribute__((ext_vector_type(4)));

__device__ inline uint16_t f2bf(float x) {
    union { float f; uint32_t u; } v; v.f = x;
    uint32_t u = v.u;
    return (uint16_t)((u + 0x7FFFu + ((u >> 16) & 1u)) >> 16);
}

// ---------------- prep: fp32 weights -> bf16 (scale 1/sqrt(D) folded into W_theta)
__global__ __launch_bounds__(256) void prep_weights(
    const float* __restrict__ wt, const float* __restrict__ wp,
    const float* __restrict__ wg, const float* __restrict__ wo,
    uint16_t* __restrict__ bwt, uint16_t* __restrict__ bwp,
    uint16_t* __restrict__ bwg, uint16_t* __restrict__ bwo)
{
    int i = blockIdx.x * 256 + threadIdx.x;   // 0..32767
    const float scale = 0.08838834764831845f; // 1/sqrt(128)
    bwt[i] = f2bf(wt[i] * scale);
    bwp[i] = f2bf(wp[i]);
    bwg[i] = f2bf(wg[i]);
    bwo[i] = f2bf(wo[i]);
}

// ---------------- projections: z=0 qp[B][N][D], z=1 kp[B][N][D], z=2 vpT[B][D][N]
// GEMM orientation: A = W[d][c] (M=d), B = src[c][n] (N-side = n), K = C.
__global__ __launch_bounds__(256) void proj_kernel(
    const float* __restrict__ q, const float* __restrict__ k, const float* __restrict__ v,
    const uint16_t* __restrict__ bwt, const uint16_t* __restrict__ bwp, const uint16_t* __restrict__ bwg,
    uint16_t* __restrict__ qp, uint16_t* __restrict__ kp, uint16_t* __restrict__ vpT)
{
    const int which = blockIdx.z;
    const float* src = (which == 0) ? q : ((which == 1) ? k : v);
    const uint16_t* w = (which == 0) ? bwt : ((which == 1) ? bwp : bwg);
    const int b   = blockIdx.y;
    const int n0  = blockIdx.x * 64;
    const int wav = threadIdx.x >> 6;
    const int lane = threadIdx.x & 63;
    const int col = lane & 15;
    const int quad = lane >> 4;
    const int n = n0 + wav * 16 + col;

    const float* srcb = src + (size_t)b * C_ * N_;

    f32x4 acc[8];
#pragma unroll
    for (int mf = 0; mf < 8; ++mf) acc[mf] = (f32x4){0.f, 0.f, 0.f, 0.f};

    for (int kc = 0; kc < 8; ++kc) {
        const int cbase = kc * 32 + quad * 8;
        // B-frag: src[c][n], lane holds k = cbase..cbase+7 at its n (strided fp32 loads)
        u16x8 bb;
#pragma unroll
        for (int j = 0; j < 8; ++j)
            bb[j] = f2bf(srcb[(size_t)(cbase + j) * N_ + n]);
        bf16x8 bfrag = __builtin_bit_cast(bf16x8, bb);
#pragma unroll
        for (int mf = 0; mf < 8; ++mf) {
            // A-frag: w[d = mf*16+col][cbase .. cbase+7], contiguous 16B
            bf16x8 afrag = *(const bf16x8*)(w + (size_t)(mf * 16 + col) * C_ + cbase);
            acc[mf] = __builtin_amdgcn_mfma_f32_16x16x32_bf16(afrag, bfrag, acc[mf], 0, 0, 0);
        }
    }

    if (which < 2) {
        uint16_t* dst = (which == 0) ? qp : kp;          // [B][N][D], d contiguous
        uint16_t* base = dst + ((size_t)b * N_ + n) * D_;
#pragma unroll
        for (int mf = 0; mf < 8; ++mf) {
            u16x4 pk;
#pragma unroll
            for (int r = 0; r < 4; ++r) pk[r] = f2bf(acc[mf][r]);
            *(u16x4*)(base + mf * 16 + quad * 4) = pk;   // 4 consecutive d, 8B store
        }
    } else {
        uint16_t* base = vpT + (size_t)b * D_ * N_;       // [B][D][N], n contiguous
#pragma unroll
        for (int mf = 0; mf < 8; ++mf)
#pragma unroll
            for (int r = 0; r < 4; ++r) {
                int d = mf * 16 + quad * 4 + r;
                base[(size_t)d * N_ + n] = f2bf(acc[mf][r]);
            }
    }
}

// ---------------- pass 1: inv_denom[b][m] = 1 / sum_n exp(S[n][m])
// one block owns m-stripe of 64 (4 m-frags), KP frags hoisted to registers; waves split n.
__global__ __launch_bounds__(256) void pass1_denom(
    const uint16_t* __restrict__ qp, const uint16_t* __restrict__ kp,
    float* __restrict__ inv_denom)
{
    const int b  = blockIdx.y;
    const int m0 = blockIdx.x * 64;
    const int wav = threadIdx.x >> 6;
    const int lane = threadIdx.x & 63;
    const int col = lane & 15;
    const int quad = lane >> 4;

    const uint16_t* qpb = qp + (size_t)b * N_ * D_;
    const uint16_t* kpb = kp + (size_t)b * N_ * D_;

    bf16x8 bfr[4][4];
#pragma unroll
    for (int mf = 0; mf < 4; ++mf)
#pragma unroll
        for (int kc = 0; kc < 4; ++kc)
            bfr[mf][kc] = *(const bf16x8*)(kpb + (size_t)(m0 + mf * 16 + col) * D_ + kc * 32 + quad * 8);

    float colsum[4] = {0.f, 0.f, 0.f, 0.f};

    for (int it = 0; it < 64; ++it) {
        const int nbase = it * 64 + wav * 16;
        bf16x8 afr[4];
#pragma unroll
        for (int kc = 0; kc < 4; ++kc)
            afr[kc] = *(const bf16x8*)(qpb + (size_t)(nbase + col) * D_ + kc * 32 + quad * 8);
#pragma unroll
        for (int mf = 0; mf < 4; ++mf) {
            f32x4 acc = (f32x4){0.f, 0.f, 0.f, 0.f};
#pragma unroll
            for (int kc = 0; kc < 4; ++kc)
                acc = __builtin_amdgcn_mfma_f32_16x16x32_bf16(afr[kc], bfr[mf][kc], acc, 0, 0, 0);
#pragma unroll
            for (int r = 0; r < 4; ++r)
                colsum[mf] += __expf(acc[r]);
        }
    }

    __shared__ float cs[4][64];
#pragma unroll
    for (int mf = 0; mf < 4; ++mf) {
        float s = colsum[mf];
        s += __shfl_down(s, 16, 64);
        s += __shfl_down(s, 32, 64);
        if (quad == 0) cs[wav][mf * 16 + col] = s;
    }
    __syncthreads();
    if (threadIdx.x < 64) {
        float s = cs[0][threadIdx.x] + cs[1][threadIdx.x] + cs[2][threadIdx.x] + cs[3][threadIdx.x];
        inv_denom[(size_t)b * N_ + m0 + threadIdx.x] = 1.0f / s;
    }
}

// ---------------- pass 2: O[n][d] = sum_m exp(S[n][m]) * inv_denom[m] * vp[m][d]
// block = 64 n-rows (wave owns 16), loop m in chunks of 32; P goes C-layout -> LDS -> A-layout.
// Round-3 restructure: ALL 16 global b128 loads of an iteration are issued as one
// batch at the top of the body and held in named registers (kpf[8], vf0[4], vf1[4]).
// Round-2's VGPR_Count=60 proved the compiler was scheduling loads one-at-a-time
// (min-register), exposing ~16 x 275 cyc of L2 latency per iteration (~4.4k cyc/iter
// measured). __launch_bounds__(256,2) allows up to 256 VGPR; grid is 2 waves/EU anyway.
__global__ __launch_bounds__(256, 2) void pass2_attn(
    const uint16_t* __restrict__ qp, const uint16_t* __restrict__ kp,
    const uint16_t* __restrict__ vpT, const float* __restrict__ inv_denom,
    uint16_t* __restrict__ obuf)
{
    const int b  = blockIdx.y;
    const int n0 = blockIdx.x * 64;
    const int wav = threadIdx.x >> 6;
    const int lane = threadIdx.x & 63;
    const int col = lane & 15;
    const int quad = lane >> 4;

    const uint16_t* qpb = qp + (size_t)b * N_ * D_;
    const uint16_t* kpb = kp + (size_t)b * N_ * D_;
    const uint16_t* vtb = vpT + (size_t)b * D_ * N_;
    const float* invd = inv_denom + (size_t)b * N_;

    __shared__ __align__(16) uint16_t plds_all[4][16][40];  // +8 pad breaks b128 read conflicts
    uint16_t (*plds)[40] = plds_all[wav];

    const int nrow = n0 + wav * 16 + col;
    bf16x8 qfr[4];
#pragma unroll
    for (int kc = 0; kc < 4; ++kc)
        qfr[kc] = *(const bf16x8*)(qpb + (size_t)nrow * D_ + kc * 32 + quad * 8);

    f32x4 oacc[8];
#pragma unroll
    for (int df = 0; df < 8; ++df) oacc[df] = (f32x4){0.f, 0.f, 0.f, 0.f};

    // hoisted base pointers for the batched loads
    const uint16_t* kp_l = kpb + (size_t)col * D_ + quad * 8;          // + (m0+f*16)*D_ + kc*32
    const uint16_t* vt_l = vtb + (size_t)col * N_ + quad * 8;          // + (df*16)*N_ + m0

    for (int m0 = 0; m0 < N_; m0 += 32) {
        // ---- batch-issue ALL global loads for this iteration ----
        bf16x8 kpf[8];   // S-side B-frags: [f][kc]
#pragma unroll
        for (int f = 0; f < 2; ++f)
#pragma unroll
            for (int kc = 0; kc < 4; ++kc)
                kpf[f * 4 + kc] = *(const bf16x8*)(kp_l + (size_t)(m0 + f * 16) * D_ + kc * 32);
        bf16x8 vf0[4];   // PV B-frags, df 0..3
#pragma unroll
        for (int df = 0; df < 4; ++df)
            vf0[df] = *(const bf16x8*)(vt_l + (size_t)(df * 16) * N_ + m0);
        bf16x8 vf1[4];   // PV B-frags, df 4..7
#pragma unroll
        for (int df = 0; df < 4; ++df)
            vf1[df] = *(const bf16x8*)(vt_l + (size_t)((df + 4) * 16) * N_ + m0);

        // ---- S = QP . KP^T for this 16n x 32m chunk, exp, -> LDS ----
#pragma unroll
        for (int f = 0; f < 2; ++f) {
            f32x4 sacc = (f32x4){0.f, 0.f, 0.f, 0.f};
#pragma unroll
            for (int kc = 0; kc < 4; ++kc)
                sacc = __builtin_amdgcn_mfma_f32_16x16x32_bf16(qfr[kc], kpf[f * 4 + kc], sacc, 0, 0, 0);
            const float inv = invd[m0 + f * 16 + col];   // lane's m column
#pragma unroll
            for (int r = 0; r < 4; ++r)
                plds[quad * 4 + r][f * 16 + col] = f2bf(__expf(sacc[r]) * inv);
        }
        // no barrier: per-wave LDS region, in-order DS + lgkmcnt ordering suffices
        bf16x8 pfrag = *(const bf16x8*)&plds[col][quad * 8];   // A-layout: n=col, k=m chunk
#pragma unroll
        for (int df = 0; df < 4; ++df)
            oacc[df] = __builtin_amdgcn_mfma_f32_16x16x32_bf16(pfrag, vf0[df], oacc[df], 0, 0, 0);
#pragma unroll
        for (int df = 0; df < 4; ++df)
            oacc[df + 4] = __builtin_amdgcn_mfma_f32_16x16x32_bf16(pfrag, vf1[df], oacc[df + 4], 0, 0, 0);
    }

    uint16_t* ob = obuf + ((size_t)b * N_ + n0 + wav * 16) * D_;   // [B][N][D]
#pragma unroll
    for (int df = 0; df < 8; ++df)
#pragma unroll
        for (int r = 0; r < 4; ++r)
            ob[(size_t)(quad * 4 + r) * D_ + df * 16 + col] = f2bf(oacc[df][r]);
}

// ---------------- pass 3: out[b][c][n] = v[b][c][n] + sum_d W_out[c][d] * O[n][d]
__global__ __launch_bounds__(256) void pass3_out(
    const uint16_t* __restrict__ obuf, const uint16_t* __restrict__ bwo,
    const float* __restrict__ v, float* __restrict__ out)
{
    const int b  = blockIdx.y;
    const int n0 = blockIdx.x * 64;
    const int wav = threadIdx.x >> 6;
    const int lane = threadIdx.x & 63;
    const int col = lane & 15;
    const int quad = lane >> 4;
    const int n = n0 + wav * 16 + col;

    const uint16_t* ob = obuf + (size_t)b * N_ * D_;
    const float* vb = v + (size_t)b * C_ * N_;
    float* outb = out + (size_t)b * C_ * N_;

    bf16x8 bfr[4];
#pragma unroll
    for (int kc = 0; kc < 4; ++kc)
        bfr[kc] = *(const bf16x8*)(ob + (size_t)n * D_ + kc * 32 + quad * 8);

#pragma unroll
    for (int cf = 0; cf < 16; ++cf) {
        f32x4 acc = (f32x4){0.f, 0.f, 0.f, 0.f};
#pragma unroll
        for (int kc = 0; kc < 4; ++kc) {
            bf16x8 afr = *(const bf16x8*)(bwo + (size_t)(cf * 16 + col) * D_ + kc * 32 + quad * 8);
            acc = __builtin_amdgcn_mfma_f32_16x16x32_bf16(afr, bfr[kc], acc, 0, 0, 0);
        }
#pragma unroll
        for (int r = 0; r < 4; ++r) {
            const int c = cf * 16 + quad * 4 + r;
            const size_t idx = (size_t)c * N_ + n;
            outb[idx] = vb[idx] + acc[r];
        }
    }
}

extern "C" void kernel_launch(void* const* d_in, const int* in_sizes, int n_in,
                              void* d_out, int out_size, void* d_ws, size_t ws_size,
                              hipStream_t stream) {
    const float* q  = (const float*)d_in[0];
    const float* k  = (const float*)d_in[1];
    const float* v  = (const float*)d_in[2];
    const float* wt = (const float*)d_in[3];
    const float* wp = (const float*)d_in[4];
    const float* wg = (const float*)d_in[5];
    const float* wo = (const float*)d_in[6];
    float* out = (float*)d_out;

    const size_t PROJ = (size_t)B_ * N_ * D_;   // 4,194,304 elems
    uint16_t* qp   = (uint16_t*)d_ws;
    uint16_t* kp   = qp + PROJ;
    uint16_t* vpT  = kp + PROJ;
    uint16_t* obuf = vpT + PROJ;
    uint16_t* bwt  = obuf + PROJ;
    uint16_t* bwp  = bwt + (size_t)D_ * C_;
    uint16_t* bwg  = bwp + (size_t)D_ * C_;
    uint16_t* bwo  = bwg + (size_t)D_ * C_;
    float* invd    = (float*)(bwo + (size_t)D_ * C_);
    // total ws use: 4*8MB + 4*64KB + 128KB ≈ 34 MB

    prep_weights<<<dim3(128), 256, 0, stream>>>(wt, wp, wg, wo, bwt, bwp, bwg, bwo);
    proj_kernel<<<dim3(N_ / 64, B_, 3), 256, 0, stream>>>(q, k, v, bwt, bwp, bwg, qp, kp, vpT);
    pass1_denom<<<dim3(N_ / 64, B_), 256, 0, stream>>>(qp, kp, invd);
    pass2_attn<<<dim3(N_ / 64, B_), 256, 0, stream>>>(qp, kp, vpT, invd, obuf);
    pass3_out<<<dim3(N_ / 64, B_), 256, 0, stream>>>(obuf, bwo, v, out);
}